// Round 6
// baseline (1092.999 us; speedup 1.0000x reference)
//
#include <hip/hip_runtime.h>
#include <stdint.h>

// Baum-Welch forward-backward posteriors (log_gamma), MI355X gfx950.
//
// R5 -> R6: R5 was still latency-bound (VALUBusy 40%, ~2670 cyc/step).
// Root cause: the compiler emits s_waitcnt vmcnt(0) before every s_barrier,
// so per-step "prefetched" global loads (emission gather, bwd alpha row)
// are drained INTO every step's critical path. Fix:
//  - 8-step chunks: all global loads batched in a chunk preamble (8 gathers,
//    bwd +8 alpha rows, into registers). One drain per chunk, not per step.
//    Steady-state barriers have no outstanding vmem -> cheap.
//  - Combine critical path cut: uniform normalizer = rcp(avec[0]) and
//    b = exp2(lB) computed in the DOT phase; fwd combine = 8-way tree sum
//    + 1 mul + LDS write.
//  - bwd gamma output (log2f chain) moved to the dot phase, deferred one
//    step via the 3-cell sacc rotation (R5-proven). gout column j is
//    thread-private in bwd -> no races.
// Skeleton unchanged: 512 thr (8 waves, 2/SIMD), wave g reduces 32-chunk,
// f2 accumulate -> v_pk_fma_f32, 2 barriers/step, d_ws unused.

#define NB 256
#define TT 512
#define KK 256
#define VV 4096
#define LOG2E 1.44269504088896f
#define LN2 0.693147180559945f

typedef float f2 __attribute__((ext_vector_type(2)));
typedef float f4 __attribute__((ext_vector_type(4)));

// MODE 0: forward (writes scaled alpha). MODE 1: backward + fused gamma.
template <int MODE>
__global__ __launch_bounds__(512, 2) void hmm_recur(
    const float* __restrict__ lpi, const float* __restrict__ lA,
    const float* __restrict__ lB, const int* __restrict__ obs,
    float* __restrict__ gout) {
  const int n = blockIdx.x;
  const int tid = threadIdx.x;  // 0..511
  const int g = tid >> 6;       // wave id = eighth of the reduction axis
  const int c = tid & 63;       // lane id
  const int j = tid;            // state index (active when j < KK)

  __shared__ int obs_s[TT];      // 2 KB
  __shared__ f4 avec4[KK / 4];   // 1 KB staged per-step vector
  __shared__ float part[8][KK];  // 8 KB per-wave partial sums
  __shared__ float abuf[8][KK];  // 8 KB alpha row buffer (fwd)
  __shared__ float sacc[4];      // bwd gamma-sum cells (3-cell rotation)
  float* avec = reinterpret_cast<float*>(avec4);

  for (int i = tid; i < TT; i += 512) obs_s[i] = obs[n * TT + i];
  if (MODE == 1 && tid < 4) sacc[tid] = 0.f;
  __syncthreads();  // obs_s + sacc ready

  // Register-resident exp(A): wave g, reduction chunk [32g, 32g+32).
  // fwd: apair[q][k] = ( expA[32g+2k][c+64q], expA[32g+2k+1][c+64q] )
  // bwd: apair[q][k] = ( expA[c+64q][32g+2k], expA[c+64q][32g+2k+1] )
  f2 apair[4][16];
  {
    const int base = g * 32;
#pragma unroll
    for (int k = 0; k < 16; ++k) {
#pragma unroll
      for (int q = 0; q < 4; ++q) {
        const int col = c + 64 * q;
        float e0, e1;
        if (MODE == 0) {
          e0 = lA[(size_t)(base + 2 * k) * KK + col];
          e1 = lA[(size_t)(base + 2 * k + 1) * KK + col];
        } else {
          e0 = lA[(size_t)col * KK + base + 2 * k];
          e1 = lA[(size_t)col * KK + base + 2 * k + 1];
        }
        f2 p;
        p[0] = exp2f(e0 * LOG2E);
        p[1] = exp2f(e1 * LOG2E);
        apair[q][k] = p;
      }
    }
  }

  // p[q] = sum over this wave's 32-chunk of avec * A-column(c+64q).
  auto dot4 = [&](float p[4]) {
    f2 acc0[4], acc1[4];
#pragma unroll
    for (int q = 0; q < 4; ++q) { acc0[q] = (f2)0.f; acc1[q] = (f2)0.f; }
    const f4* av = &avec4[g * 8];
#pragma unroll
    for (int m4 = 0; m4 < 8; ++m4) {
      f4 x = av[m4];
      f2 x0; x0[0] = x[0]; x0[1] = x[1];
      f2 x1; x1[0] = x[2]; x1[1] = x[3];
#pragma unroll
      for (int q = 0; q < 4; ++q) {
        acc0[q] += x0 * apair[q][2 * m4];
        acc1[q] += x1 * apair[q][2 * m4 + 1];
      }
    }
#pragma unroll
    for (int q = 0; q < 4; ++q)
      p[q] = (acc0[q][0] + acc0[q][1]) + (acc1[q][0] + acc1[q][1]);
  };

  if (MODE == 0) {
    // ---- forward: chunks of 8 steps ----
    float braw[8];
#pragma unroll 1
    for (int k = 0; k < 64; ++k) {
      // flush previous chunk's alpha rows (wave g -> row 8(k-1)+g)
      if (k > 0) {
        f4 v = *(const f4*)&abuf[g][c * 4];
        *(f4*)&gout[((size_t)n * TT + (8 * (k - 1) + g)) * KK + c * 4] = v;
      }
      // batched emission gathers for steps 8k..8k+7
      if (j < KK) {
#pragma unroll
        for (int i = 0; i < 8; ++i)
          braw[i] = lB[(size_t)j * VV + obs_s[8 * k + i]];
      }
#pragma unroll
      for (int i = 0; i < 8; ++i) {
        const int t = 8 * k + i;
        if (k == 0 && i == 0) {
          if (j < KK) {
            float u = exp2f((lpi[j] + braw[0]) * LOG2E);
            avec[j] = u;
            abuf[0][j] = u;
          }
          __syncthreads();
        } else {
          // dot phase: normalizer + emission prepared off the combine path
          float s0 = avec[0];  // broadcast LDS read
          float b = exp2f(braw[i] * LOG2E);
          float k1 = __builtin_amdgcn_rcpf(s0) * b;
          float p[4];
          dot4(p);
          part[g][c] = p[0];
          part[g][c + 64] = p[1];
          part[g][c + 128] = p[2];
          part[g][c + 192] = p[3];
          __syncthreads();  // barrier A: partials visible
          if (j < KK) {
            float cs = ((part[0][j] + part[1][j]) + (part[2][j] + part[3][j])) +
                       ((part[4][j] + part[5][j]) + (part[6][j] + part[7][j]));
            float u2 = cs * k1;  // uniform scale cancels in gamma
            avec[j] = u2;
            abuf[i][j] = u2;
          }
          __syncthreads();  // barrier B: avec staged
        }
      }
    }
    {  // epilogue: flush chunk 63 (rows 504..511)
      f4 v = *(const f4*)&abuf[g][c * 4];
      *(f4*)&gout[((size_t)n * TT + (504 + g)) * KK + c * 4] = v;
    }
  } else {
    // ---- backward + fused gamma: descending chunks of 8 steps ----
    float braw[8], avrow[8];
    float ggreg = 0.f;
    size_t rowreg = ((size_t)n * TT + (TT - 1)) * KK + j;
#pragma unroll 1
    for (int k = 63; k >= 0; --k) {
      // batched loads for steps 8k..8k+7 (emission + alpha rows).
      // gout column j is private to thread j in bwd: reads of rows
      // 8k..8k+7 precede this thread's own deferred overwrites of them.
      if (j < KK) {
#pragma unroll
        for (int i = 0; i < 8; ++i) {
          const int t = 8 * k + i;
          braw[i] = lB[(size_t)j * VV + obs_s[t]];
          avrow[i] = gout[((size_t)n * TT + t) * KK + j];
        }
      }
#pragma unroll
      for (int i = 7; i >= 0; --i) {
        const int t = 8 * k + i;
        if (k == 63 && i == 7) {
          if (j < KK) {
            float w = exp2f(braw[7] * LOG2E);  // staged w_{T-1}
            avec[j] = w;
            ggreg = avrow[7];  // gamma numerator (beta=1)
            float s = avrow[7];
#pragma unroll
            for (int d = 1; d < 64; d <<= 1) s += __shfl_xor(s, d);
            if (c == 0) atomicAdd(&sacc[(TT - 1) % 3], s);
          }
          __syncthreads();
        } else {
          // dot phase: emit deferred output for step t+1; prep scale + b
          float s0 = avec[0];
          float b = exp2f(braw[i] * LOG2E);
          float k0 = __builtin_amdgcn_rcpf(s0);
          if (j < KK) {
            float s2 = sacc[(t + 1) % 3];  // complete since last barrier
            gout[rowreg] = (log2f(ggreg) - log2f(s2)) * LN2;
          }
          float p[4];
          dot4(p);
          part[g][c] = p[0];
          part[g][c + 64] = p[1];
          part[g][c + 128] = p[2];
          part[g][c + 192] = p[3];
          __syncthreads();  // barrier A
          if (j < KK) {
            float cs = ((part[0][j] + part[1][j]) + (part[2][j] + part[3][j])) +
                       ((part[4][j] + part[5][j]) + (part[6][j] + part[7][j]));
            float bu = cs * k0;       // beta_t (uniform scale)
            float gg = avrow[i] * bu; // gamma numerator, step t
            avec[j] = bu * b;         // staged w_t
            float s = gg;
#pragma unroll
            for (int d = 1; d < 64; d <<= 1) s += __shfl_xor(s, d);
            if (c == 0) atomicAdd(&sacc[t % 3], s);
            ggreg = gg;
            rowreg = ((size_t)n * TT + t) * KK + j;
          }
          if (tid == 0) sacc[(t + 2) % 3] = 0.f;  // recycle (used at t-1)
          __syncthreads();  // barrier B
        }
      }
    }
    if (j < KK) {  // final deferred row (t=0)
      float s2 = sacc[0];
      gout[rowreg] = (log2f(ggreg) - log2f(s2)) * LN2;
    }
  }
}

extern "C" void kernel_launch(void* const* d_in, const int* in_sizes, int n_in,
                              void* d_out, int out_size, void* d_ws, size_t ws_size,
                              hipStream_t stream) {
  const float* lpi = (const float*)d_in[0];
  const float* lA = (const float*)d_in[1];
  const float* lB = (const float*)d_in[2];
  const int* obs = (const int*)d_in[3];
  float* gout = (float*)d_out;
  (void)d_ws; (void)ws_size;  // deliberately unused

  hmm_recur<0><<<NB, 512, 0, stream>>>(lpi, lA, lB, obs, gout);
  hmm_recur<1><<<NB, 512, 0, stream>>>(lpi, lA, lB, obs, gout);
}